// Round 3
// baseline (1479.389 us; speedup 1.0000x reference)
//
#include <hip/hip_runtime.h>
#include <stdint.h>

#define NLEV 16
#define LOG2_T 19
#define TMASK ((1u << LOG2_T) - 1u)
#define P1 2654435761u
#define P2 805459861u

typedef float floatx4 __attribute__((ext_vector_type(4)));
typedef float floatx2 __attribute__((ext_vector_type(2)));

// Compute level-l hash indices + fracs and ISSUE the 8 gathers (no wait).
__device__ __forceinline__ void issue_level(
    int l, float xn, float yn, float zn,
    const floatx2* __restrict__ table,
    floatx2* f, float* fr)
{
    const float res = (float)(16 << l);          // floor(16*2^l) exact
    const float posx = xn * res;
    const float posy = yn * res;
    const float posz = zn * res;
    const float flx = floorf(posx);
    const float fly = floorf(posy);
    const float flz = floorf(posz);
    fr[0] = posx - flx;
    fr[1] = posy - fly;
    fr[2] = posz - flz;
    const int ix = (int)flx, iy = (int)fly, iz = (int)flz;

    const uint32_t hx0 = (uint32_t)ix;
    const uint32_t hx1 = (uint32_t)(ix + 1);
    const uint32_t hy0 = (uint32_t)iy * P1;
    const uint32_t hy1 = (uint32_t)(iy + 1) * P1;
    const uint32_t hz0 = (uint32_t)iz * P2;
    const uint32_t hz1 = (uint32_t)(iz + 1) * P2;

    const floatx2* __restrict__ tbl = table + ((size_t)l << LOG2_T);

    uint32_t idx[8];
    idx[0] = (hx0 ^ hy0 ^ hz0) & TMASK;
    idx[1] = (hx0 ^ hy0 ^ hz1) & TMASK;
    idx[2] = (hx0 ^ hy1 ^ hz0) & TMASK;
    idx[3] = (hx0 ^ hy1 ^ hz1) & TMASK;
    idx[4] = (hx1 ^ hy0 ^ hz0) & TMASK;
    idx[5] = (hx1 ^ hy0 ^ hz1) & TMASK;
    idx[6] = (hx1 ^ hy1 ^ hz0) & TMASK;
    idx[7] = (hx1 ^ hy1 ^ hz1) & TMASK;

    #pragma unroll
    for (int c = 0; c < 8; ++c) f[c] = tbl[idx[c]];
}

__global__ __launch_bounds__(256) void hashenc_kernel(
    const float* __restrict__ x,
    const float* __restrict__ bb,
    const float* __restrict__ table_f,
    float* __restrict__ enc_out,
    float* __restrict__ mask_out,
    int n)
{
    int i = blockIdx.x * blockDim.x + threadIdx.x;
    if (i >= n) return;

    const float bx0 = bb[0], by0 = bb[1], bz0 = bb[2];
    const float bx1 = bb[3], by1 = bb[4], bz1 = bb[5];

    const float px = x[3 * i + 0];
    const float py = x[3 * i + 1];
    const float pz = x[3 * i + 2];

    // exact fp32 ops to match numpy reference (no rcp/fast-math)
    const float xn = (px - bx0) / (bx1 - bx0);
    const float yn = (py - by0) / (by1 - by0);
    const float zn = (pz - bz0) / (bz1 - bz0);

    const bool inb = (xn > 0.0f) & (xn < 1.0f) &
                     (yn > 0.0f) & (yn < 1.0f) &
                     (zn > 0.0f) & (zn < 1.0f);

    const floatx2* table = (const floatx2*)table_f;

    float enc[2 * NLEV];

    // software pipeline: level l+1's gathers in flight while consuming level l
    floatx2 fA[8];
    float frA[3];
    issue_level(0, xn, yn, zn, table, fA, frA);

    #pragma unroll
    for (int l = 0; l < NLEV; ++l) {
        floatx2 fB[8];
        float frB[3];
        if (l + 1 < NLEV)
            issue_level(l + 1, xn, yn, zn, table, fB, frB);

        const float fx = frA[0], fy = frA[1], fz = frA[2];
        const float gx = 1.0f - fx, gy = 1.0f - fy, gz = 1.0f - fz;
        const float wx[2] = {gx, fx};
        const float wy[2] = {gy, fy};
        const float wz[2] = {gz, fz};

        float s0 = 0.0f, s1 = 0.0f;
        #pragma unroll
        for (int c = 0; c < 8; ++c) {
            const float w = (wx[(c >> 2) & 1] * wy[(c >> 1) & 1]) * wz[c & 1];
            s0 = fmaf(w, fA[c].x, s0);
            s1 = fmaf(w, fA[c].y, s1);
        }
        enc[2 * l + 0] = s0;
        enc[2 * l + 1] = s1;

        // rotate pipeline (register renames after full unroll)
        #pragma unroll
        for (int c = 0; c < 8; ++c) fA[c] = fB[c];
        frA[0] = frB[0]; frA[1] = frB[1]; frA[2] = frB[2];
    }

    // vectorized non-temporal stores: don't evict table lines from L2
    floatx4* o = (floatx4*)(enc_out + (size_t)i * (2 * NLEV));
    #pragma unroll
    for (int k = 0; k < (2 * NLEV) / 4; ++k) {
        floatx4 v = { enc[4 * k + 0], enc[4 * k + 1],
                      enc[4 * k + 2], enc[4 * k + 3] };
        __builtin_nontemporal_store(v, o + k);
    }
    __builtin_nontemporal_store(inb ? 1.0f : 0.0f, mask_out + i);
}

extern "C" void kernel_launch(void* const* d_in, const int* in_sizes, int n_in,
                              void* d_out, int out_size, void* d_ws, size_t ws_size,
                              hipStream_t stream) {
    const float* x     = (const float*)d_in[0];
    const float* bb    = (const float*)d_in[1];
    const float* table = (const float*)d_in[2];
    const int n = in_sizes[0] / 3;

    float* enc_out  = (float*)d_out;
    float* mask_out = enc_out + (size_t)n * (2 * NLEV);

    const int block = 256;
    const int grid = (n + block - 1) / block;
    hashenc_kernel<<<grid, block, 0, stream>>>(x, bb, table, enc_out, mask_out, n);
}

// Round 4
// 1304.206 us; speedup vs baseline: 1.1343x; 1.1343x over previous
//
#include <hip/hip_runtime.h>
#include <stdint.h>

#define NLEV 16
#define LOG2_T 19
#define TMASK ((1u << LOG2_T) - 1u)
#define P1 2654435761u
#define P2 805459861u

#define PTS 8                   // points per thread
#define BLOCK 256
#define CHUNK (BLOCK * PTS)     // 2048 points per block
#define NGROUPS 4               // level groups; group = blockIdx % 4 -> XCD % 4
#define LPG 4                   // levels per group (consecutive -> contiguous 32B output)

typedef float floatx4 __attribute__((ext_vector_type(4)));
typedef float floatx2 __attribute__((ext_vector_type(2)));

__global__ __launch_bounds__(BLOCK) void hashenc_grouped(
    const float* __restrict__ x,
    const float* __restrict__ bb,
    const float* __restrict__ table_f,
    float* __restrict__ enc_out,
    float* __restrict__ mask_out,
    int n)
{
    const int g     = blockIdx.x & (NGROUPS - 1);   // level group; XCD = blockIdx%8 -> one group per XCD
    const int chunk = blockIdx.x >> 2;
    const int base  = chunk * CHUNK + (int)threadIdx.x;

    const float bx0 = bb[0], by0 = bb[1], bz0 = bb[2];
    const float bx1 = bb[3], by1 = bb[4], bz1 = bb[5];

    // Load points once; exact fp32 ops to match numpy reference.
    float xn[PTS], yn[PTS], zn[PTS];
    bool valid[PTS], inb[PTS];
    #pragma unroll
    for (int k = 0; k < PTS; ++k) {
        const int p = base + k * BLOCK;
        valid[k] = (p < n);
        const int q = valid[k] ? p : 0;
        const float px = x[3 * q + 0];
        const float py = x[3 * q + 1];
        const float pz = x[3 * q + 2];
        xn[k] = (px - bx0) / (bx1 - bx0);
        yn[k] = (py - by0) / (by1 - by0);
        zn[k] = (pz - bz0) / (bz1 - bz0);
        inb[k] = (xn[k] > 0.f) & (xn[k] < 1.f) &
                 (yn[k] > 0.f) & (yn[k] < 1.f) &
                 (zn[k] > 0.f) & (zn[k] < 1.f);
    }

    float acc[PTS][LPG][2];
    #pragma unroll
    for (int k = 0; k < PTS; ++k)
        #pragma unroll
        for (int j = 0; j < LPG; ++j)
            acc[k][j][0] = acc[k][j][1] = 0.f;

    const floatx2* __restrict__ table = (const floatx2*)table_f;

    // Level loop OUTER: one ~4MiB table hot in this XCD's L2 at a time.
    #pragma unroll
    for (int li = 0; li < LPG; ++li) {
        const int l = g * LPG + li;
        const float res = (float)(16 << l);              // floor(16*2^l) exact
        const floatx2* __restrict__ tbl = table + ((size_t)l << LOG2_T);

        #pragma unroll
        for (int k = 0; k < PTS; ++k) {
            const float posx = xn[k] * res;
            const float posy = yn[k] * res;
            const float posz = zn[k] * res;
            const float flx = floorf(posx);
            const float fly = floorf(posy);
            const float flz = floorf(posz);
            const float fx = posx - flx, fy = posy - fly, fz = posz - flz;
            const int ix = (int)flx, iy = (int)fly, iz = (int)flz;

            const uint32_t hx0 = (uint32_t)ix;
            const uint32_t hx1 = (uint32_t)(ix + 1);
            const uint32_t hy0 = (uint32_t)iy * P1;
            const uint32_t hy1 = (uint32_t)(iy + 1) * P1;
            const uint32_t hz0 = (uint32_t)iz * P2;
            const uint32_t hz1 = (uint32_t)(iz + 1) * P2;

            uint32_t idx[8];
            idx[0] = (hx0 ^ hy0 ^ hz0) & TMASK;
            idx[1] = (hx0 ^ hy0 ^ hz1) & TMASK;
            idx[2] = (hx0 ^ hy1 ^ hz0) & TMASK;
            idx[3] = (hx0 ^ hy1 ^ hz1) & TMASK;
            idx[4] = (hx1 ^ hy0 ^ hz0) & TMASK;
            idx[5] = (hx1 ^ hy0 ^ hz1) & TMASK;
            idx[6] = (hx1 ^ hy1 ^ hz0) & TMASK;
            idx[7] = (hx1 ^ hy1 ^ hz1) & TMASK;

            floatx2 f[8];
            #pragma unroll
            for (int c = 0; c < 8; ++c) f[c] = tbl[idx[c]];

            const float gx = 1.f - fx, gy = 1.f - fy, gz = 1.f - fz;
            const float wx[2] = {gx, fx};
            const float wy[2] = {gy, fy};
            const float wz[2] = {gz, fz};

            float s0 = 0.f, s1 = 0.f;
            #pragma unroll
            for (int c = 0; c < 8; ++c) {
                const float w = (wx[(c >> 2) & 1] * wy[(c >> 1) & 1]) * wz[c & 1];
                s0 = fmaf(w, f[c].x, s0);
                s1 = fmaf(w, f[c].y, s1);
            }
            acc[k][li][0] = s0;
            acc[k][li][1] = s1;
        }
    }

    // 32 contiguous bytes per point per group; aligned non-temporal stores.
    #pragma unroll
    for (int k = 0; k < PTS; ++k) {
        if (!valid[k]) continue;
        const int p = base + k * BLOCK;
        float* row = enc_out + (size_t)p * (2 * NLEV) + g * (2 * LPG);
        floatx4 v0 = { acc[k][0][0], acc[k][0][1], acc[k][1][0], acc[k][1][1] };
        floatx4 v1 = { acc[k][2][0], acc[k][2][1], acc[k][3][0], acc[k][3][1] };
        __builtin_nontemporal_store(v0, (floatx4*)row + 0);
        __builtin_nontemporal_store(v1, (floatx4*)row + 1);
        if (g == 0)
            __builtin_nontemporal_store(inb[k] ? 1.0f : 0.0f, mask_out + p);
    }
}

extern "C" void kernel_launch(void* const* d_in, const int* in_sizes, int n_in,
                              void* d_out, int out_size, void* d_ws, size_t ws_size,
                              hipStream_t stream) {
    const float* x     = (const float*)d_in[0];
    const float* bb    = (const float*)d_in[1];
    const float* table = (const float*)d_in[2];
    const int n = in_sizes[0] / 3;

    float* enc_out  = (float*)d_out;
    float* mask_out = enc_out + (size_t)n * (2 * NLEV);

    const int chunks = (n + CHUNK - 1) / CHUNK;
    const int grid = NGROUPS * chunks;
    hashenc_grouped<<<grid, BLOCK, 0, stream>>>(x, bb, table, enc_out, mask_out, n);
}

// Round 5
// 1074.598 us; speedup vs baseline: 1.3767x; 1.2137x over previous
//
#include <hip/hip_runtime.h>
#include <stdint.h>

#define NLEV 16
#define LOG2_T 19
#define TMASK ((1u << LOG2_T) - 1u)
#define P1 2654435761u
#define P2 805459861u

typedef float floatx4 __attribute__((ext_vector_type(4)));
typedef float floatx2 __attribute__((ext_vector_type(2)));

#define PTS1 4
#define BLOCK1 256
#define CHUNK1 (BLOCK1 * PTS1)   // 1024 points per block

// ---- shared helper: one point, one level (exact fp32 to match numpy ref) ----
__device__ __forceinline__ floatx2 encode_point_level(
    float xn, float yn, float zn, float res,
    const floatx2* __restrict__ tbl)
{
    const float posx = xn * res;
    const float posy = yn * res;
    const float posz = zn * res;
    const float flx = floorf(posx);
    const float fly = floorf(posy);
    const float flz = floorf(posz);
    const float fx = posx - flx, fy = posy - fly, fz = posz - flz;
    const int ix = (int)flx, iy = (int)fly, iz = (int)flz;

    const uint32_t hx0 = (uint32_t)ix;
    const uint32_t hx1 = (uint32_t)(ix + 1);
    const uint32_t hy0 = (uint32_t)iy * P1;
    const uint32_t hy1 = (uint32_t)(iy + 1) * P1;
    const uint32_t hz0 = (uint32_t)iz * P2;
    const uint32_t hz1 = (uint32_t)(iz + 1) * P2;

    uint32_t idx[8];
    idx[0] = (hx0 ^ hy0 ^ hz0) & TMASK;
    idx[1] = (hx0 ^ hy0 ^ hz1) & TMASK;
    idx[2] = (hx0 ^ hy1 ^ hz0) & TMASK;
    idx[3] = (hx0 ^ hy1 ^ hz1) & TMASK;
    idx[4] = (hx1 ^ hy0 ^ hz0) & TMASK;
    idx[5] = (hx1 ^ hy0 ^ hz1) & TMASK;
    idx[6] = (hx1 ^ hy1 ^ hz0) & TMASK;
    idx[7] = (hx1 ^ hy1 ^ hz1) & TMASK;

    floatx2 f[8];
    #pragma unroll
    for (int c = 0; c < 8; ++c) f[c] = tbl[idx[c]];

    const float gx = 1.f - fx, gy = 1.f - fy, gz = 1.f - fz;
    const float wx[2] = {gx, fx};
    const float wy[2] = {gy, fy};
    const float wz[2] = {gz, fz};

    float s0 = 0.f, s1 = 0.f;
    #pragma unroll
    for (int c = 0; c < 8; ++c) {
        const float w = (wx[(c >> 2) & 1] * wy[(c >> 1) & 1]) * wz[c & 1];
        s0 = fmaf(w, f[c].x, s0);
        s1 = fmaf(w, f[c].y, s1);
    }
    floatx2 r = {s0, s1};
    return r;
}

// ---- phase 1: one level per XCD (level = base + blockIdx%8), ws[l][N][2] ----
__global__ __launch_bounds__(BLOCK1) void level_kernel(
    const float* __restrict__ x,
    const float* __restrict__ bb,
    const float* __restrict__ table_f,
    float* __restrict__ ws,
    int n, int level_base)
{
    const int level = level_base + (int)(blockIdx.x & 7);
    const int chunk = (int)(blockIdx.x >> 3);
    const int base  = chunk * CHUNK1 + (int)threadIdx.x;

    const float bx0 = bb[0], by0 = bb[1], bz0 = bb[2];
    const float bx1 = bb[3], by1 = bb[4], bz1 = bb[5];

    const float res = (float)(16 << level);      // floor(16*2^l) exact
    const floatx2* __restrict__ tbl =
        (const floatx2*)table_f + ((size_t)level << LOG2_T);
    floatx2* __restrict__ wrow = (floatx2*)ws + (size_t)level * n;

    #pragma unroll
    for (int k = 0; k < PTS1; ++k) {
        const int p = base + k * BLOCK1;
        if (p >= n) continue;
        const float px = x[3 * p + 0];
        const float py = x[3 * p + 1];
        const float pz = x[3 * p + 2];
        const float xn = (px - bx0) / (bx1 - bx0);
        const float yn = (py - by0) / (by1 - by0);
        const float zn = (pz - bz0) / (bz1 - bz0);
        floatx2 r = encode_point_level(xn, yn, zn, res, tbl);
        // non-temporal: don't evict the resident table from L2
        __builtin_nontemporal_store(r, wrow + p);
    }
}

// ---- phase 2: transpose ws[16][N][2] -> enc[N][32], compute mask ----
__global__ __launch_bounds__(256) void transpose_kernel(
    const float* __restrict__ ws,
    const float* __restrict__ x,
    const float* __restrict__ bb,
    float* __restrict__ enc_out,
    float* __restrict__ mask_out,
    int n)
{
    const int p = blockIdx.x * 256 + (int)threadIdx.x;
    if (p >= n) return;

    const floatx2* __restrict__ w = (const floatx2*)ws;

    float row[2 * NLEV];
    #pragma unroll
    for (int l = 0; l < NLEV; ++l) {
        floatx2 v = w[(size_t)l * n + p];        // lane-contiguous: coalesced
        row[2 * l + 0] = v.x;
        row[2 * l + 1] = v.y;
    }

    const float bx0 = bb[0], by0 = bb[1], bz0 = bb[2];
    const float bx1 = bb[3], by1 = bb[4], bz1 = bb[5];
    const float xn = (x[3 * p + 0] - bx0) / (bx1 - bx0);
    const float yn = (x[3 * p + 1] - by0) / (by1 - by0);
    const float zn = (x[3 * p + 2] - bz0) / (bz1 - bz0);
    const bool inb = (xn > 0.f) & (xn < 1.f) &
                     (yn > 0.f) & (yn < 1.f) &
                     (zn > 0.f) & (zn < 1.f);

    floatx4* o = (floatx4*)(enc_out + (size_t)p * (2 * NLEV));
    #pragma unroll
    for (int k = 0; k < (2 * NLEV) / 4; ++k) {
        floatx4 v = { row[4 * k + 0], row[4 * k + 1],
                      row[4 * k + 2], row[4 * k + 3] };
        __builtin_nontemporal_store(v, o + k);
    }
    __builtin_nontemporal_store(inb ? 1.0f : 0.0f, mask_out + p);
}

// ---- fallback: direct single-kernel version (R1, verified correct) ----
__global__ __launch_bounds__(256) void hashenc_direct(
    const float* __restrict__ x,
    const float* __restrict__ bb,
    const float* __restrict__ table_f,
    float* __restrict__ enc_out,
    float* __restrict__ mask_out,
    int n)
{
    const int i = blockIdx.x * 256 + (int)threadIdx.x;
    if (i >= n) return;

    const float bx0 = bb[0], by0 = bb[1], bz0 = bb[2];
    const float bx1 = bb[3], by1 = bb[4], bz1 = bb[5];
    const float xn = (x[3 * i + 0] - bx0) / (bx1 - bx0);
    const float yn = (x[3 * i + 1] - by0) / (by1 - by0);
    const float zn = (x[3 * i + 2] - bz0) / (bz1 - bz0);
    const bool inb = (xn > 0.f) & (xn < 1.f) &
                     (yn > 0.f) & (yn < 1.f) &
                     (zn > 0.f) & (zn < 1.f);

    const floatx2* table = (const floatx2*)table_f;
    float enc[2 * NLEV];
    for (int l = 0; l < NLEV; ++l) {
        const float res = (float)(16 << l);
        floatx2 r = encode_point_level(xn, yn, zn, res,
                                       table + ((size_t)l << LOG2_T));
        enc[2 * l + 0] = r.x;
        enc[2 * l + 1] = r.y;
    }
    floatx4* o = (floatx4*)(enc_out + (size_t)i * (2 * NLEV));
    #pragma unroll
    for (int k = 0; k < (2 * NLEV) / 4; ++k) {
        floatx4 v = { enc[4 * k + 0], enc[4 * k + 1],
                      enc[4 * k + 2], enc[4 * k + 3] };
        __builtin_nontemporal_store(v, o + k);
    }
    __builtin_nontemporal_store(inb ? 1.0f : 0.0f, mask_out + i);
}

extern "C" void kernel_launch(void* const* d_in, const int* in_sizes, int n_in,
                              void* d_out, int out_size, void* d_ws, size_t ws_size,
                              hipStream_t stream) {
    const float* x     = (const float*)d_in[0];
    const float* bb    = (const float*)d_in[1];
    const float* table = (const float*)d_in[2];
    const int n = in_sizes[0] / 3;

    float* enc_out  = (float*)d_out;
    float* mask_out = enc_out + (size_t)n * (2 * NLEV);

    const size_t ws_need = (size_t)NLEV * (size_t)n * 2 * sizeof(float);
    if (ws_size >= ws_need) {
        float* ws = (float*)d_ws;
        const int chunks = (n + CHUNK1 - 1) / CHUNK1;
        const int grid1 = chunks * 8;
        level_kernel<<<grid1, BLOCK1, 0, stream>>>(x, bb, table, ws, n, 0);
        level_kernel<<<grid1, BLOCK1, 0, stream>>>(x, bb, table, ws, n, 8);
        const int grid2 = (n + 255) / 256;
        transpose_kernel<<<grid2, 256, 0, stream>>>(ws, x, bb, enc_out, mask_out, n);
    } else {
        const int grid = (n + 255) / 256;
        hashenc_direct<<<grid, 256, 0, stream>>>(x, bb, table, enc_out, mask_out, n);
    }
}